// Round 7
// baseline (28.738 us; speedup 1.0000x reference)
//
#include <hip/hip_runtime.h>

// out = P*noise + (1-P)*(latent @ W + b), P = prod_{t=1..steps} t/steps
// (closed form of the reference's affine scan)
//
// R6 structure (winning shape: simple per-row loop, per-lane W fragments,
// VALU-only DPP reduce) with two targeted changes:
//  1. wave -> 4 CONSECUTIVE rows (unit-stride 16KB stream per wave,
//     vs 32MB-strided grid-stride rows)
//  2. nontemporal loads for latent (pure streaming; no reuse exists --
//     harness's 512MB fills wipe L3 between replays anyway)

typedef float f32x4 __attribute__((ext_vector_type(4)));

constexpr int D = 1024;

template <int CTRL>
__device__ __forceinline__ float dpp_add(float x) {
    int s = __builtin_amdgcn_update_dpp(0, __float_as_int(x), CTRL, 0xf, 0xf, true);
    return x + __int_as_float(s);
}

// full-wave sum; result valid in lane 63
__device__ __forceinline__ float wave_sum_dpp(float x) {
    x = dpp_add<0x111>(x);  // row_shr:1
    x = dpp_add<0x112>(x);  // row_shr:2
    x = dpp_add<0x114>(x);  // row_shr:4
    x = dpp_add<0x118>(x);  // row_shr:8  -> lanes 15/31/47/63 = 16-lane sums
    x = dpp_add<0x142>(x);  // row_bcast:15 -> lanes 31,63 = 32-lane sums
    x = dpp_add<0x143>(x);  // row_bcast:31 -> lane 63 = full sum
    return x;
}

__global__ __launch_bounds__(256) void diff_init_kernel(
    const float* __restrict__ latent,   // [rows][1024]
    const float* __restrict__ W,        // [1024][3]
    const float* __restrict__ bvec,     // [3]
    const float* __restrict__ noise,    // [rows][3]
    const int*   __restrict__ steps_p,  // scalar
    float*       __restrict__ out,      // [rows][3]
    int rows)
{
    const int lane = threadIdx.x & 63;
    const int wave = blockIdx.x * (blockDim.x >> 6) + (threadIdx.x >> 6);
    const int row0 = wave * 4;
    if (row0 >= rows) return;

    const int steps = steps_p[0];
    float P = 1.0f;
    for (int t = steps; t >= 1; --t) P *= (float)t / (float)steps;
    const float Q = 1.0f - P;

    // Per-lane W fragment: float4-chunk idx = it*64+lane covers d in
    // [idx*4, idx*4+4); 4 d's x 3 cols = 12 consecutive floats at idx*48 B.
    float w[4][12];
    #pragma unroll
    for (int it = 0; it < 4; ++it) {
        const f32x4* wp = (const f32x4*)(W + (size_t)(it * 64 + lane) * 12);
        f32x4 wa = wp[0], wb = wp[1], wc = wp[2];
        w[it][0] = wa.x; w[it][1]  = wa.y; w[it][2]  = wa.z; w[it][3]  = wa.w;
        w[it][4] = wb.x; w[it][5]  = wb.y; w[it][6]  = wb.z; w[it][7]  = wb.w;
        w[it][8] = wc.x; w[it][9]  = wc.y; w[it][10] = wc.z; w[it][11] = wc.w;
    }

    const float bb = (lane < 3) ? bvec[lane] : 0.0f;
    const int rend = (row0 + 4 <= rows) ? row0 + 4 : rows;

    for (int row = row0; row < rend; ++row) {
        const f32x4* lrow = (const f32x4*)(latent + (size_t)row * D);
        // issue noise load early so its latency hides under the FMAs
        const float nz = (lane < 3) ? noise[(size_t)row * 3 + lane] : 0.0f;

        float a0 = 0.f, a1 = 0.f, a2 = 0.f;
        #pragma unroll
        for (int it = 0; it < 4; ++it) {
            f32x4 lv = __builtin_nontemporal_load(lrow + it * 64 + lane);
            a0 = fmaf(lv.x, w[it][0], a0);
            a1 = fmaf(lv.x, w[it][1], a1);
            a2 = fmaf(lv.x, w[it][2], a2);
            a0 = fmaf(lv.y, w[it][3], a0);
            a1 = fmaf(lv.y, w[it][4], a1);
            a2 = fmaf(lv.y, w[it][5], a2);
            a0 = fmaf(lv.z, w[it][6], a0);
            a1 = fmaf(lv.z, w[it][7], a1);
            a2 = fmaf(lv.z, w[it][8], a2);
            a0 = fmaf(lv.w, w[it][9],  a0);
            a1 = fmaf(lv.w, w[it][10], a1);
            a2 = fmaf(lv.w, w[it][11], a2);
        }

        // VALU-only reduce: 3 independent DPP chains, totals in lane 63
        const float sa = wave_sum_dpp(a0);
        const float sb = wave_sum_dpp(a1);
        const float sc = wave_sum_dpp(a2);
        const float ra = __int_as_float(__builtin_amdgcn_readlane(__float_as_int(sa), 63));
        const float rb = __int_as_float(__builtin_amdgcn_readlane(__float_as_int(sb), 63));
        const float rc = __int_as_float(__builtin_amdgcn_readlane(__float_as_int(sc), 63));

        if (lane < 3) {
            const float t = (lane == 0) ? ra : (lane == 1) ? rb : rc;
            out[(size_t)row * 3 + lane] = fmaf(P, nz, Q * (t + bb));
        }
    }
}

extern "C" void kernel_launch(void* const* d_in, const int* in_sizes, int n_in,
                              void* d_out, int out_size, void* d_ws, size_t ws_size,
                              hipStream_t stream) {
    const float* latent = (const float*)d_in[0];
    const float* W      = (const float*)d_in[1];
    const float* bvec   = (const float*)d_in[2];
    const float* noise  = (const float*)d_in[3];
    const int*   steps  = (const int*)d_in[4];
    float* out = (float*)d_out;

    const int rows   = in_sizes[0] / D;            // 4*8192 = 32768
    const int waves  = (rows + 3) / 4;             // 4 consecutive rows / wave
    const int blocks = (waves + 3) / 4;            // 4 waves / block -> 2048
    diff_init_kernel<<<blocks, 256, 0, stream>>>(latent, W, bvec, noise, steps,
                                                 out, rows);
}